// Round 1
// baseline (455.379 us; speedup 1.0000x reference)
//
#include <hip/hip_runtime.h>
#include <hip/hip_bf16.h>
#include <stdint.h>

#define B_   64
#define L_   512
#define E_   256
#define P_   64
#define KOUT 512
#define KS_  3
#define H_   512
#define T_   53
#define CIN  896            // 3E + 2P
#define LP   (L_ + 2)       // zero-padded rows per batch

typedef __attribute__((ext_vector_type(8))) short bf16x8;
typedef __attribute__((ext_vector_type(4))) float f32x4;

__device__ __forceinline__ unsigned enc_f(float x) {
    unsigned u = __float_as_uint(x);
    return (u & 0x80000000u) ? ~u : (u | 0x80000000u);
}
__device__ __forceinline__ float dec_f(unsigned e) {
    return __uint_as_float((e & 0x80000000u) ? (e & 0x7fffffffu) : ~e);
}

// async global->LDS, 16B per lane; LDS dest must be wave-uniform base + lane*16
__device__ __forceinline__ void cp16(const void* g, void* l) {
    __builtin_amdgcn_global_load_lds(
        (const __attribute__((address_space(1))) unsigned int*)g,
        (__attribute__((address_space(3))) unsigned int*)l,
        16, 0, 0);
}

// ---------------------------------------------------------------------------
// Repack conv_w (K, Cin, KS) fp32 -> wb[t][n][c] bf16 (tap-major, row-major n x c)
__global__ void repack_w(const float* __restrict__ conv_w,
                         __hip_bfloat16* __restrict__ wb) {
    int o = blockIdx.x * 256 + threadIdx.x;
    const int total = KS_ * KOUT * CIN;
    if (o >= total) return;
    int c = o % CIN;
    int n = (o / CIN) % KOUT;
    int t = o / (CIN * KOUT);
    wb[o] = __float2bfloat16(conv_w[(n * CIN + c) * KS_ + t]);
}

// ---------------------------------------------------------------------------
// Build padded bf16 sent tensor: (B, LP, CIN); rows lp=0 and lp=LP-1 are zero.
// Row lp=l+1: [emb(l-1)|0, emb(l), emb(l+1)|0, pos_s(l), pos_o(l)]
__global__ void build_sentp(const int* __restrict__ context,
                            const int* __restrict__ sdis,
                            const int* __restrict__ odis,
                            const float* __restrict__ etab,
                            const float* __restrict__ ptab,
                            __hip_bfloat16* __restrict__ sentp) {
    int row = blockIdx.x;                 // 0 .. B*LP-1
    int b = row / LP;
    int lp = row % LP;
    __hip_bfloat16* out = sentp + (size_t)row * CIN;
    if (lp == 0 || lp == LP - 1) {
        for (int e = threadIdx.x; e < CIN; e += 256) out[e] = __float2bfloat16(0.f);
        return;
    }
    int l = lp - 1;
    const int* ctx = context + b * L_;
    int ts = sdis[b * L_ + l], to = odis[b * L_ + l];
    for (int e = threadIdx.x; e < CIN; e += 256) {
        float v;
        if (e < 3 * E_) {
            int seg = e >> 8;             // E_ == 256
            int dim = e & 255;
            int x = l - 1 + seg;
            v = (x >= 0 && x < L_) ? etab[(size_t)ctx[x] * E_ + dim] : 0.f;
        } else if (e < 3 * E_ + P_) {
            v = ptab[(size_t)ts * P_ + (e - 3 * E_)];
        } else {
            v = ptab[(size_t)to * P_ + (e - 3 * E_ - P_)];
        }
        out[e] = __float2bfloat16(v);
    }
}

// ---------------------------------------------------------------------------
// Entity span features: ent(b, which) = [mean over span, left, right] (768 fp32)
__global__ void entity_feats(const int* __restrict__ context,
                             const int* __restrict__ sidx,
                             const int* __restrict__ oidx,
                             const float* __restrict__ etab,
                             float* __restrict__ ent) {   // (B, 1536)
    int b = blockIdx.x;
    int which = blockIdx.y;               // 0 = subj, 1 = obj
    const int* idx = which ? oidx : sidx;
    int s = idx[b * 2 + 0], e = idx[b * 2 + 1];
    const int* ctx = context + b * L_;
    float* outb = ent + (size_t)b * 1536 + which * 768;
    int d = threadIdx.x;                  // 256 threads == E_
    float sum = 0.f;
    for (int x = s; x <= e; ++x) sum += etab[(size_t)ctx[x] * E_ + d];
    outb[d] = sum / (float)(e - s + 1);
    outb[256 + d] = etab[(size_t)ctx[s - 1] * E_ + d];
    float r = 0.f;
    if (e + 1 < L_) r = etab[(size_t)ctx[e + 1] * E_ + d];
    outb[512 + d] = r;
}

// ---------------------------------------------------------------------------
// conv (as 3-tap GEMM, bf16 MFMA) fused with maxpool over L.
// C[m=(b,l), n=k] = sum_t sum_c sentp[b, l+t, c] * wb[t][n][c]
// grid: (256 M-tiles, 4 N-tiles), block 256 = 4 waves, 128x128 tile, BK=32.
__global__ void conv_gemm_pool(const __hip_bfloat16* __restrict__ sentp,
                               const __hip_bfloat16* __restrict__ wb,
                               unsigned* __restrict__ pooled) {
    __shared__ __hip_bfloat16 sA[128 * 32];   // 8 KB, row-major, 64B rows
    __shared__ __hip_bfloat16 sB[128 * 32];   // 8 KB

    const int tid  = threadIdx.x;
    const int wave = tid >> 6;
    const int lane = tid & 63;
    const int mt = blockIdx.x;            // 0..255
    const int nt = blockIdx.y;            // 0..3
    const int b  = mt >> 2;
    const int l0 = (mt & 3) * 128;
    const int n0 = nt * 128;

    const int wr = (wave & 1) * 64;       // wave row offset within tile
    const int wc = (wave >> 1) * 64;      // wave col offset within tile
    const int m  = lane & 15;
    const int q  = lane >> 4;

    f32x4 acc[4][4];
#pragma unroll
    for (int i = 0; i < 4; i++)
#pragma unroll
        for (int j = 0; j < 4; j++) acc[i][j] = (f32x4){0.f, 0.f, 0.f, 0.f};

    const int rowA0 = tid >> 2;           // staging row, round 0
    const int colA0 = (tid & 3) * 16;     // byte offset within 64B row
    const int rowA1 = (tid + 256) >> 2;

    for (int t = 0; t < KS_; ++t) {
        const char* Abase = (const char*)sentp + ((size_t)(b * LP + l0 + t) * CIN) * 2;
        const char* Bbase = (const char*)wb + ((size_t)(t * KOUT + n0) * CIN) * 2;
        for (int kc = 0; kc < CIN; kc += 32) {
            const char* Ab = Abase + kc * 2;
            const char* Bb = Bbase + kc * 2;
            cp16(Ab + rowA0 * (CIN * 2) + colA0, (char*)sA + tid * 16);
            cp16(Bb + rowA0 * (CIN * 2) + colA0, (char*)sB + tid * 16);
            cp16(Ab + rowA1 * (CIN * 2) + colA0, (char*)sA + (tid + 256) * 16);
            cp16(Bb + rowA1 * (CIN * 2) + colA0, (char*)sB + (tid + 256) * 16);
            __syncthreads();

            bf16x8 af[4], bfr[4];
#pragma unroll
            for (int i = 0; i < 4; i++)
                af[i] = *(const bf16x8*)((const char*)sA + (wr + i * 16 + m) * 64 + q * 16);
#pragma unroll
            for (int j = 0; j < 4; j++)
                bfr[j] = *(const bf16x8*)((const char*)sB + (wc + j * 16 + m) * 64 + q * 16);
#pragma unroll
            for (int i = 0; i < 4; i++)
#pragma unroll
                for (int j = 0; j < 4; j++)
                    acc[i][j] = __builtin_amdgcn_mfma_f32_16x16x32_bf16(
                        af[i], bfr[j], acc[i][j], 0, 0, 0);
            __syncthreads();
        }
    }

    // maxpool epilogue: lane holds, for each j, 16 rows (4 i-tiles x 4 regs), one col.
#pragma unroll
    for (int j = 0; j < 4; j++) {
        float mx = -3.4e38f;
#pragma unroll
        for (int i = 0; i < 4; i++)
#pragma unroll
            for (int r = 0; r < 4; r++) mx = fmaxf(mx, acc[i][j][r]);
        mx = fmaxf(mx, __shfl_xor(mx, 16, 64));
        mx = fmaxf(mx, __shfl_xor(mx, 32, 64));
        if (q == 0) {
            int col = n0 + wc + j * 16 + m;
            atomicMax(&pooled[b * KOUT + col], enc_f(mx));
        }
    }
}

// ---------------------------------------------------------------------------
// Final: sent_h = tanh(pooled @ lin1_w^T + b1); com=[subj,obj,sent_h]; scores.
__global__ void final_k(const unsigned* __restrict__ pooled,
                        const float* __restrict__ conv_b,
                        const float* __restrict__ lin1_w,
                        const float* __restrict__ lin1_b,
                        const float* __restrict__ lin2_w,
                        const float* __restrict__ lin2_b,
                        const float* __restrict__ ent,
                        float* __restrict__ out) {
    __shared__ float pool_l[KOUT];
    __shared__ float com[2048];
    int b = blockIdx.x, tid = threadIdx.x;
    for (int k = tid; k < KOUT; k += 256)
        pool_l[k] = dec_f(pooled[b * KOUT + k]) + conv_b[k];
    for (int c = tid; c < 1536; c += 256)
        com[c] = ent[(size_t)b * 1536 + c];
    __syncthreads();
    for (int h = tid; h < H_; h += 256) {
        float s = lin1_b[h];
        const float* w = lin1_w + (size_t)h * KOUT;
        for (int k = 0; k < KOUT; ++k) s += pool_l[k] * w[k];
        com[1536 + h] = tanhf(s);
    }
    __syncthreads();
    int wave = tid >> 6, lane = tid & 63;
    for (int t = wave; t < T_; t += 4) {
        const float* w = lin2_w + (size_t)t * 2048;
        float s = 0.f;
        for (int c = lane; c < 2048; c += 64) s += com[c] * w[c];
        for (int off = 32; off > 0; off >>= 1) s += __shfl_down(s, off, 64);
        if (lane == 0) out[b * T_ + t] = s + lin2_b[t];
    }
}

// ---------------------------------------------------------------------------
extern "C" void kernel_launch(void* const* d_in, const int* in_sizes, int n_in,
                              void* d_out, int out_size, void* d_ws, size_t ws_size,
                              hipStream_t stream) {
    const int*   context = (const int*)d_in[0];
    const int*   sidx    = (const int*)d_in[1];
    const int*   oidx    = (const int*)d_in[2];
    const int*   sdis    = (const int*)d_in[3];
    const int*   odis    = (const int*)d_in[4];
    const float* etab    = (const float*)d_in[5];
    const float* ptab    = (const float*)d_in[6];
    const float* conv_w  = (const float*)d_in[7];
    const float* conv_b  = (const float*)d_in[8];
    const float* lin1_w  = (const float*)d_in[9];
    const float* lin1_b  = (const float*)d_in[10];
    const float* lin2_w  = (const float*)d_in[11];
    const float* lin2_b  = (const float*)d_in[12];
    float* out = (float*)d_out;

    char* ws = (char*)d_ws;
    size_t off = 0;
    __hip_bfloat16* sentp = (__hip_bfloat16*)(ws + off);
    off += (size_t)B_ * LP * CIN * 2;            // ~58.9 MB
    off = (off + 255) & ~(size_t)255;
    __hip_bfloat16* wb = (__hip_bfloat16*)(ws + off);
    off += (size_t)KS_ * KOUT * CIN * 2;         // ~2.75 MB
    off = (off + 255) & ~(size_t)255;
    unsigned* pooled = (unsigned*)(ws + off);
    off += (size_t)B_ * KOUT * 4;                // 128 KB
    off = (off + 255) & ~(size_t)255;
    float* ent = (float*)(ws + off);
    off += (size_t)B_ * 1536 * 4;                // 384 KB

    // pooled init: enc==0 is below every real float encoding
    hipMemsetAsync(pooled, 0, (size_t)B_ * KOUT * 4, stream);

    repack_w<<<dim3((KS_ * KOUT * CIN + 255) / 256), dim3(256), 0, stream>>>(conv_w, wb);
    build_sentp<<<dim3(B_ * LP), dim3(256), 0, stream>>>(context, sdis, odis, etab, ptab, sentp);
    entity_feats<<<dim3(B_, 2), dim3(256), 0, stream>>>(context, sidx, oidx, etab, ent);
    conv_gemm_pool<<<dim3(256, 4), dim3(256), 0, stream>>>(sentp, wb, pooled);
    final_k<<<dim3(B_), dim3(256), 0, stream>>>(pooled, conv_b, lin1_w, lin1_b,
                                                lin2_w, lin2_b, ent, out);
}

// Round 2
// 303.405 us; speedup vs baseline: 1.5009x; 1.5009x over previous
//
#include <hip/hip_runtime.h>
#include <hip/hip_bf16.h>
#include <stdint.h>

#define B_   64
#define L_   512
#define E_   256
#define P_   64
#define KOUT 512
#define KS_  3
#define H_   512
#define T_   53
#define CIN  896            // 3E + 2P
#define LP   (L_ + 2)       // zero-padded rows per batch
#define COMW 2048           // 1536 ent + 512 sent_h

typedef __attribute__((ext_vector_type(8))) short bf16x8;
typedef __attribute__((ext_vector_type(4))) float f32x4;

__device__ __forceinline__ unsigned enc_f(float x) {
    unsigned u = __float_as_uint(x);
    return (u & 0x80000000u) ? ~u : (u | 0x80000000u);
}
__device__ __forceinline__ float dec_f(unsigned e) {
    return __uint_as_float((e & 0x80000000u) ? (e & 0x7fffffffu) : ~e);
}

// async global->LDS, 16B per lane; LDS dest must be wave-uniform base + lane*16
__device__ __forceinline__ void cp16(const void* g, void* l) {
    __builtin_amdgcn_global_load_lds(
        (const __attribute__((address_space(1))) unsigned int*)g,
        (__attribute__((address_space(3))) unsigned int*)l,
        16, 0, 0);
}

// ---------------------------------------------------------------------------
// Repack conv_w (K, Cin, KS) fp32 -> wb[t][n][c] bf16 (tap-major, row-major n x c)
__global__ void repack_w(const float* __restrict__ conv_w,
                         __hip_bfloat16* __restrict__ wb) {
    int o = blockIdx.x * 256 + threadIdx.x;
    const int total = KS_ * KOUT * CIN;
    if (o >= total) return;
    int c = o % CIN;
    int n = (o / CIN) % KOUT;
    int t = o / (CIN * KOUT);
    wb[o] = __float2bfloat16(conv_w[(n * CIN + c) * KS_ + t]);
}

// ---------------------------------------------------------------------------
// Build padded bf16 sent tensor: (B, LP, CIN); rows lp=0 and lp=LP-1 are zero.
// Row lp=l+1: [emb(l-1)|0, emb(l), emb(l+1)|0, pos_s(l), pos_o(l)]
__global__ void build_sentp(const int* __restrict__ context,
                            const int* __restrict__ sdis,
                            const int* __restrict__ odis,
                            const float* __restrict__ etab,
                            const float* __restrict__ ptab,
                            __hip_bfloat16* __restrict__ sentp) {
    int row = blockIdx.x;                 // 0 .. B*LP-1
    int b = row / LP;
    int lp = row % LP;
    __hip_bfloat16* out = sentp + (size_t)row * CIN;
    if (lp == 0 || lp == LP - 1) {
        for (int e = threadIdx.x; e < CIN; e += 256) out[e] = __float2bfloat16(0.f);
        return;
    }
    int l = lp - 1;
    const int* ctx = context + b * L_;
    int ts = sdis[b * L_ + l], to = odis[b * L_ + l];
    for (int e = threadIdx.x; e < CIN; e += 256) {
        float v;
        if (e < 3 * E_) {
            int seg = e >> 8;             // E_ == 256
            int dim = e & 255;
            int x = l - 1 + seg;
            v = (x >= 0 && x < L_) ? etab[(size_t)ctx[x] * E_ + dim] : 0.f;
        } else if (e < 3 * E_ + P_) {
            v = ptab[(size_t)ts * P_ + (e - 3 * E_)];
        } else {
            v = ptab[(size_t)to * P_ + (e - 3 * E_ - P_)];
        }
        out[e] = __float2bfloat16(v);
    }
}

// ---------------------------------------------------------------------------
// Entity span features -> com buffer rows [0,1536): [mean, left, right] x {subj,obj}
__global__ void entity_feats(const int* __restrict__ context,
                             const int* __restrict__ sidx,
                             const int* __restrict__ oidx,
                             const float* __restrict__ etab,
                             float* __restrict__ com) {   // (B, COMW)
    int b = blockIdx.x;
    int which = blockIdx.y;               // 0 = subj, 1 = obj
    const int* idx = which ? oidx : sidx;
    int s = idx[b * 2 + 0], e = idx[b * 2 + 1];
    const int* ctx = context + b * L_;
    float* outb = com + (size_t)b * COMW + which * 768;
    int d = threadIdx.x;                  // 256 threads == E_
    float sum = 0.f;
    for (int x = s; x <= e; ++x) sum += etab[(size_t)ctx[x] * E_ + d];
    outb[d] = sum / (float)(e - s + 1);
    outb[256 + d] = etab[(size_t)ctx[s - 1] * E_ + d];
    float r = 0.f;
    if (e + 1 < L_) r = etab[(size_t)ctx[e + 1] * E_ + d];
    outb[512 + d] = r;
}

// ---------------------------------------------------------------------------
// conv (as 3-tap GEMM, bf16 MFMA) fused with maxpool over L.
__global__ void conv_gemm_pool(const __hip_bfloat16* __restrict__ sentp,
                               const __hip_bfloat16* __restrict__ wb,
                               unsigned* __restrict__ pooled) {
    __shared__ __hip_bfloat16 sA[128 * 32];   // 8 KB, row-major, 64B rows
    __shared__ __hip_bfloat16 sB[128 * 32];   // 8 KB

    const int tid  = threadIdx.x;
    const int wave = tid >> 6;
    const int lane = tid & 63;
    const int mt = blockIdx.x;            // 0..255
    const int nt = blockIdx.y;            // 0..3
    const int b  = mt >> 2;
    const int l0 = (mt & 3) * 128;
    const int n0 = nt * 128;

    const int wr = (wave & 1) * 64;
    const int wc = (wave >> 1) * 64;
    const int m  = lane & 15;
    const int q  = lane >> 4;

    f32x4 acc[4][4];
#pragma unroll
    for (int i = 0; i < 4; i++)
#pragma unroll
        for (int j = 0; j < 4; j++) acc[i][j] = (f32x4){0.f, 0.f, 0.f, 0.f};

    const int rowA0 = tid >> 2;
    const int colA0 = (tid & 3) * 16;
    const int rowA1 = (tid + 256) >> 2;

    for (int t = 0; t < KS_; ++t) {
        const char* Abase = (const char*)sentp + ((size_t)(b * LP + l0 + t) * CIN) * 2;
        const char* Bbase = (const char*)wb + ((size_t)(t * KOUT + n0) * CIN) * 2;
        for (int kc = 0; kc < CIN; kc += 32) {
            const char* Ab = Abase + kc * 2;
            const char* Bb = Bbase + kc * 2;
            cp16(Ab + rowA0 * (CIN * 2) + colA0, (char*)sA + tid * 16);
            cp16(Bb + rowA0 * (CIN * 2) + colA0, (char*)sB + tid * 16);
            cp16(Ab + rowA1 * (CIN * 2) + colA0, (char*)sA + (tid + 256) * 16);
            cp16(Bb + rowA1 * (CIN * 2) + colA0, (char*)sB + (tid + 256) * 16);
            __syncthreads();

            bf16x8 af[4], bfr[4];
#pragma unroll
            for (int i = 0; i < 4; i++)
                af[i] = *(const bf16x8*)((const char*)sA + (wr + i * 16 + m) * 64 + q * 16);
#pragma unroll
            for (int j = 0; j < 4; j++)
                bfr[j] = *(const bf16x8*)((const char*)sB + (wc + j * 16 + m) * 64 + q * 16);
#pragma unroll
            for (int i = 0; i < 4; i++)
#pragma unroll
                for (int j = 0; j < 4; j++)
                    acc[i][j] = __builtin_amdgcn_mfma_f32_16x16x32_bf16(
                        af[i], bfr[j], acc[i][j], 0, 0, 0);
            __syncthreads();
        }
    }

#pragma unroll
    for (int j = 0; j < 4; j++) {
        float mx = -3.4e38f;
#pragma unroll
        for (int i = 0; i < 4; i++)
#pragma unroll
            for (int r = 0; r < 4; r++) mx = fmaxf(mx, acc[i][j][r]);
        mx = fmaxf(mx, __shfl_xor(mx, 16, 64));
        mx = fmaxf(mx, __shfl_xor(mx, 32, 64));
        if (q == 0) {
            int col = n0 + wc + j * 16 + m;
            atomicMax(&pooled[b * KOUT + col], enc_f(mx));
        }
    }
}

// ---------------------------------------------------------------------------
// lin1: one wave per (b,h). sent_h = tanh(pool.dot(w) + b1) -> com[:,1536+h]
__global__ void lin1_k(const unsigned* __restrict__ pooled,
                       const float* __restrict__ conv_b,
                       const float* __restrict__ lin1_w,
                       const float* __restrict__ lin1_b,
                       float* __restrict__ com) {
    int bid = blockIdx.x;                 // 0..8191
    int wave = threadIdx.x >> 6, lane = threadIdx.x & 63;
    int b = bid >> 7;                     // 64
    int h = (bid & 127) * 4 + wave;       // 512
    const float* w = lin1_w + (size_t)h * KOUT;
    const unsigned* pb = pooled + b * KOUT;
    float s = 0.f;
#pragma unroll
    for (int i = 0; i < 8; i++) {
        int k = lane + 64 * i;
        float p = dec_f(pb[k]) + conv_b[k];
        s += p * w[k];
    }
#pragma unroll
    for (int off = 32; off > 0; off >>= 1) s += __shfl_down(s, off, 64);
    if (lane == 0) com[(size_t)b * COMW + 1536 + h] = tanhf(s + lin1_b[h]);
}

// ---------------------------------------------------------------------------
// lin2: one wave per (b,t). out = com.dot(w2) + b2
__global__ void lin2_k(const float* __restrict__ com,
                       const float* __restrict__ lin2_w,
                       const float* __restrict__ lin2_b,
                       float* __restrict__ out) {
    int b = blockIdx.x;
    int wave = threadIdx.x >> 6, lane = threadIdx.x & 63;
    int t = blockIdx.y * 4 + wave;
    if (t >= T_) return;
    const float* w = lin2_w + (size_t)t * COMW;
    const float* c = com + (size_t)b * COMW;
    float s = 0.f;
#pragma unroll
    for (int i = 0; i < 32; i++) {
        int k = lane + 64 * i;
        s += c[k] * w[k];
    }
#pragma unroll
    for (int off = 32; off > 0; off >>= 1) s += __shfl_down(s, off, 64);
    if (lane == 0) out[b * T_ + t] = s + lin2_b[t];
}

// ---------------------------------------------------------------------------
extern "C" void kernel_launch(void* const* d_in, const int* in_sizes, int n_in,
                              void* d_out, int out_size, void* d_ws, size_t ws_size,
                              hipStream_t stream) {
    const int*   context = (const int*)d_in[0];
    const int*   sidx    = (const int*)d_in[1];
    const int*   oidx    = (const int*)d_in[2];
    const int*   sdis    = (const int*)d_in[3];
    const int*   odis    = (const int*)d_in[4];
    const float* etab    = (const float*)d_in[5];
    const float* ptab    = (const float*)d_in[6];
    const float* conv_w  = (const float*)d_in[7];
    const float* conv_b  = (const float*)d_in[8];
    const float* lin1_w  = (const float*)d_in[9];
    const float* lin1_b  = (const float*)d_in[10];
    const float* lin2_w  = (const float*)d_in[11];
    const float* lin2_b  = (const float*)d_in[12];
    float* out = (float*)d_out;

    char* ws = (char*)d_ws;
    size_t off = 0;
    __hip_bfloat16* sentp = (__hip_bfloat16*)(ws + off);
    off += (size_t)B_ * LP * CIN * 2;            // ~58.9 MB
    off = (off + 255) & ~(size_t)255;
    __hip_bfloat16* wb = (__hip_bfloat16*)(ws + off);
    off += (size_t)KS_ * KOUT * CIN * 2;         // ~2.75 MB
    off = (off + 255) & ~(size_t)255;
    unsigned* pooled = (unsigned*)(ws + off);
    off += (size_t)B_ * KOUT * 4;                // 128 KB
    off = (off + 255) & ~(size_t)255;
    float* com = (float*)(ws + off);
    off += (size_t)B_ * COMW * 4;                // 512 KB

    hipMemsetAsync(pooled, 0, (size_t)B_ * KOUT * 4, stream);

    repack_w<<<dim3((KS_ * KOUT * CIN + 255) / 256), dim3(256), 0, stream>>>(conv_w, wb);
    build_sentp<<<dim3(B_ * LP), dim3(256), 0, stream>>>(context, sdis, odis, etab, ptab, sentp);
    entity_feats<<<dim3(B_, 2), dim3(256), 0, stream>>>(context, sidx, oidx, etab, com);
    conv_gemm_pool<<<dim3(256, 4), dim3(256), 0, stream>>>(sentp, wb, pooled);
    lin1_k<<<dim3(8192), dim3(256), 0, stream>>>(pooled, conv_b, lin1_w, lin1_b, com);
    lin2_k<<<dim3(B_, 14), dim3(256), 0, stream>>>(com, lin2_w, lin2_b, out);
}

// Round 4
// 271.826 us; speedup vs baseline: 1.6753x; 1.1162x over previous
//
#include <hip/hip_runtime.h>
#include <hip/hip_bf16.h>
#include <stdint.h>

#define B_   64
#define L_   512
#define E_   256
#define P_   64
#define KOUT 512
#define KS_  3
#define H_   512
#define T_   53
#define CINW 2688           // conv_w inner: 896*3
#define LE   516            // embp rows/batch: L + 4 (2 zero each side)
#define LPP  514            // posp rows/batch: L + 2 (1 zero each side)
#define COMW 2048           // 1536 ent + 512 sent_h

typedef __attribute__((ext_vector_type(8))) short bf16x8;
typedef __attribute__((ext_vector_type(4))) float f32x4;

__device__ __forceinline__ unsigned enc_f(float x) {
    unsigned u = __float_as_uint(x);
    return (u & 0x80000000u) ? ~u : (u | 0x80000000u);
}
__device__ __forceinline__ float dec_f(unsigned e) {
    return __uint_as_float((e & 0x80000000u) ? (e & 0x7fffffffu) : ~e);
}

__device__ __forceinline__ void cp16(const void* g, void* l) {
    __builtin_amdgcn_global_load_lds(
        (const __attribute__((address_space(1))) unsigned int*)g,
        (__attribute__((address_space(3))) unsigned int*)l,
        16, 0, 0);
}

// ---------------------------------------------------------------------------
// Precombine conv weights.
// wce[d][n][c] = sum_{seg+tau=d} conv_w[n][(seg*256+c)*3 + tau], d in [0,5)
// wcp[tau][n][p] = conv_w[n][(768+p)*3 + tau]
__global__ void combine_w(const float* __restrict__ conv_w,
                          __hip_bfloat16* __restrict__ wce,
                          __hip_bfloat16* __restrict__ wcp) {
    int o = blockIdx.x * 256 + threadIdx.x;
    const int NE = 5 * KOUT * E_;           // 655360 (= 5<<17)
    if (o < NE) {
        int c = o & 255, n = (o >> 8) & 511, d = o >> 17;
        float s = 0.f;
#pragma unroll
        for (int tau = 0; tau <= 2; tau++) {
            int seg = d - tau;
            if (seg >= 0 && seg <= 2)
                s += conv_w[(size_t)n * CINW + (seg * 256 + c) * 3 + tau];
        }
        wce[o] = __float2bfloat16(s);
    } else {
        int o2 = o - NE;
        if (o2 < 3 * KOUT * 128) {
            int p = o2 & 127, n = (o2 >> 7) & 511, tau = o2 >> 16;
            wcp[o2] = __float2bfloat16(conv_w[(size_t)n * CINW + (768 + p) * 3 + tau]);
        }
    }
}

// ---------------------------------------------------------------------------
// embp (B, LE, E) bf16: row r = emb(r-2) for r in [2, 514), else 0. One wave/row.
__global__ void build_embp(const int* __restrict__ ctx,
                           const float* __restrict__ etab,
                           __hip_bfloat16* __restrict__ embp) {
    int row = blockIdx.x * 4 + (threadIdx.x >> 6);
    if (row >= B_ * LE) return;
    int lane = threadIdx.x & 63;
    int b = row / LE, r = row % LE;
    __hip_bfloat16* out = embp + (size_t)row * E_;
    if (r < 2 || r >= LE - 2) {
        *(ushort4*)(out + lane * 4) = (ushort4){0, 0, 0, 0};
        return;
    }
    int token = ctx[b * L_ + (r - 2)];
    float4 v = *(const float4*)(etab + (size_t)token * E_ + lane * 4);
    union { __hip_bfloat16 h[4]; ushort4 u; } pk;
    pk.h[0] = __float2bfloat16(v.x); pk.h[1] = __float2bfloat16(v.y);
    pk.h[2] = __float2bfloat16(v.z); pk.h[3] = __float2bfloat16(v.w);
    *(ushort4*)(out + lane * 4) = pk.u;
}

// ---------------------------------------------------------------------------
// posp (B, LPP, 128) bf16: row r = [pos_s(r-1), pos_o(r-1)] for r in [1,513), else 0.
__global__ void build_posp(const int* __restrict__ sdis,
                           const int* __restrict__ odis,
                           const float* __restrict__ ptab,
                           __hip_bfloat16* __restrict__ posp) {
    int row = blockIdx.x * 4 + (threadIdx.x >> 6);
    if (row >= B_ * LPP) return;          // R3 crash fix: no rows past B*LPP
    int lane = threadIdx.x & 63;
    int b = row / LPP, r = row % LPP;
    __hip_bfloat16* out = posp + (size_t)row * 128;
    if (r < 1 || r >= LPP - 1) {
        *(unsigned*)(out + lane * 2) = 0u;
        return;
    }
    int l = r - 1;
    int which = lane >> 5;                  // 0 subj, 1 obj
    int i2 = (lane & 31) * 2;
    int t = which ? odis[b * L_ + l] : sdis[b * L_ + l];
    float2 v = *(const float2*)(ptab + (size_t)t * P_ + i2);
    union { __hip_bfloat16 h[2]; unsigned u; } pk;
    pk.h[0] = __float2bfloat16(v.x); pk.h[1] = __float2bfloat16(v.y);
    *(unsigned*)(out + which * 64 + i2) = pk.u;
}

// ---------------------------------------------------------------------------
// Edge-correction terms (exact fp32): the 5-tap expansion spuriously adds
//   l=0:   emb(0)   . W[:, 2E:3E, tau=0]
//   l=511: emb(511) . W[:, 0:E,   tau=2]
// corr (B, 2, KOUT)
__global__ void corr_k(const int* __restrict__ ctx,
                       const float* __restrict__ etab,
                       const float* __restrict__ conv_w,
                       float* __restrict__ corr) {
    __shared__ float emb[E_];
    int b = blockIdx.x, which = blockIdx.y;
    int token = ctx[b * L_ + (which ? L_ - 1 : 0)];
    emb[threadIdx.x] = etab[(size_t)token * E_ + threadIdx.x];
    __syncthreads();
    for (int n = threadIdx.x; n < KOUT; n += 256) {
        const float* w = conv_w + (size_t)n * CINW + (which ? 2 : 512 * 3);
        float s = 0.f;
        for (int c = 0; c < E_; c++) s += emb[c] * w[c * 3];
        corr[(b * 2 + which) * KOUT + n] = s;
    }
}

// ---------------------------------------------------------------------------
// Entity span features -> com rows [0,1536)
__global__ void entity_feats(const int* __restrict__ context,
                             const int* __restrict__ sidx,
                             const int* __restrict__ oidx,
                             const float* __restrict__ etab,
                             float* __restrict__ com) {
    int b = blockIdx.x;
    int which = blockIdx.y;
    const int* idx = which ? oidx : sidx;
    int s = idx[b * 2 + 0], e = idx[b * 2 + 1];
    const int* ctx = context + b * L_;
    float* outb = com + (size_t)b * COMW + which * 768;
    int d = threadIdx.x;
    float sum = 0.f;
    for (int x = s; x <= e; ++x) sum += etab[(size_t)ctx[x] * E_ + d];
    outb[d] = sum / (float)(e - s + 1);
    outb[256 + d] = etab[(size_t)ctx[s - 1] * E_ + d];
    float r = 0.f;
    if (e + 1 < L_) r = etab[(size_t)ctx[e + 1] * E_ + d];
    outb[512 + d] = r;
}

// ---------------------------------------------------------------------------
// conv as 5 emb-taps + 3 pos-taps GEMM (bf16 MFMA), fused maxpool + edge corr.
// K-work 1664 (vs 2688 trigram). LDS chunk-swizzled: chunk ^= (row>>1)&3.
__global__ void conv_gemm_pool(const __hip_bfloat16* __restrict__ embp,
                               const __hip_bfloat16* __restrict__ posp,
                               const __hip_bfloat16* __restrict__ wce,
                               const __hip_bfloat16* __restrict__ wcp,
                               const float* __restrict__ corr,
                               unsigned* __restrict__ pooled) {
    __shared__ __hip_bfloat16 sA[128 * 32];
    __shared__ __hip_bfloat16 sB[128 * 32];

    const int tid  = threadIdx.x;
    const int wave = tid >> 6;
    const int lane = tid & 63;
    const int mt = blockIdx.x;
    const int nt = blockIdx.y;
    const int b  = mt >> 2;
    const int l0 = (mt & 3) * 128;
    const int n0 = nt * 128;

    const int wr = (wave & 1) * 64;
    const int wc = (wave >> 1) * 64;
    const int m  = lane & 15;
    const int q  = lane >> 4;

    f32x4 acc[4][4];
#pragma unroll
    for (int i = 0; i < 4; i++)
#pragma unroll
        for (int j = 0; j < 4; j++) acc[i][j] = (f32x4){0.f, 0.f, 0.f, 0.f};

    const int rowA = tid >> 2;
    // staging lane loads global chunk (slot ^ s(row)) so LDS holds a swizzled layout
    const int cswz = (((tid & 3) ^ ((tid >> 3) & 3))) * 16;
    const int rsw  = (q ^ ((m >> 1) & 3)) * 16;   // read-side byte offset for chunk q

    auto step = [&](const char* Ab, int AsB, const char* Bb, int BsB) {
        cp16(Ab + rowA * AsB + cswz, (char*)sA + tid * 16);
        cp16(Bb + rowA * BsB + cswz, (char*)sB + tid * 16);
        cp16(Ab + (rowA + 64) * AsB + cswz, (char*)sA + (tid + 256) * 16);
        cp16(Bb + (rowA + 64) * BsB + cswz, (char*)sB + (tid + 256) * 16);
        __syncthreads();
        bf16x8 af[4], bfr[4];
#pragma unroll
        for (int i = 0; i < 4; i++)
            af[i] = *(const bf16x8*)((const char*)sA + (wr + i * 16 + m) * 64 + rsw);
#pragma unroll
        for (int j = 0; j < 4; j++)
            bfr[j] = *(const bf16x8*)((const char*)sB + (wc + j * 16 + m) * 64 + rsw);
#pragma unroll
        for (int i = 0; i < 4; i++)
#pragma unroll
            for (int j = 0; j < 4; j++)
                acc[i][j] = __builtin_amdgcn_mfma_f32_16x16x32_bf16(
                    af[i], bfr[j], acc[i][j], 0, 0, 0);
        __syncthreads();
    };

    // emb phase: 5 taps x 8 chunks
    for (int t = 0; t < 5; t++) {
        const char* Abase = (const char*)(embp + (size_t)(b * LE + l0 + t) * E_);
        const char* Bbase = (const char*)(wce + (size_t)(t * KOUT + n0) * E_);
        for (int kc = 0; kc < E_; kc += 32)
            step(Abase + kc * 2, E_ * 2, Bbase + kc * 2, E_ * 2);
    }
    // pos phase: 3 taps x 4 chunks
    for (int t = 0; t < 3; t++) {
        const char* Abase = (const char*)(posp + (size_t)(b * LPP + l0 + t) * 128);
        const char* Bbase = (const char*)(wcp + (size_t)(t * KOUT + n0) * 128);
        for (int kc = 0; kc < 128; kc += 32)
            step(Abase + kc * 2, 256, Bbase + kc * 2, 256);
    }

    const float* corrb = corr + b * 2 * KOUT;
#pragma unroll
    for (int j = 0; j < 4; j++) {
        int col = n0 + wc + j * 16 + m;
        float mx = -3.4e38f;
#pragma unroll
        for (int i = 0; i < 4; i++)
#pragma unroll
            for (int r = 0; r < 4; r++) {
                float v = acc[i][j][r];
                int l = l0 + wr + i * 16 + q * 4 + r;
                if (l == 0)      v -= corrb[col];
                if (l == L_ - 1) v -= corrb[KOUT + col];
                mx = fmaxf(mx, v);
            }
        mx = fmaxf(mx, __shfl_xor(mx, 16, 64));
        mx = fmaxf(mx, __shfl_xor(mx, 32, 64));
        if (q == 0) atomicMax(&pooled[b * KOUT + col], enc_f(mx));
    }
}

// ---------------------------------------------------------------------------
__global__ void lin1_k(const unsigned* __restrict__ pooled,
                       const float* __restrict__ conv_b,
                       const float* __restrict__ lin1_w,
                       const float* __restrict__ lin1_b,
                       float* __restrict__ com) {
    int bid = blockIdx.x;
    int wave = threadIdx.x >> 6, lane = threadIdx.x & 63;
    int b = bid >> 7;
    int h = (bid & 127) * 4 + wave;
    const float* w = lin1_w + (size_t)h * KOUT;
    const unsigned* pb = pooled + b * KOUT;
    float s = 0.f;
#pragma unroll
    for (int i = 0; i < 8; i++) {
        int k = lane + 64 * i;
        s += (dec_f(pb[k]) + conv_b[k]) * w[k];
    }
#pragma unroll
    for (int off = 32; off > 0; off >>= 1) s += __shfl_down(s, off, 64);
    if (lane == 0) com[(size_t)b * COMW + 1536 + h] = tanhf(s + lin1_b[h]);
}

__global__ void lin2_k(const float* __restrict__ com,
                       const float* __restrict__ lin2_w,
                       const float* __restrict__ lin2_b,
                       float* __restrict__ out) {
    int b = blockIdx.x;
    int wave = threadIdx.x >> 6, lane = threadIdx.x & 63;
    int t = blockIdx.y * 4 + wave;
    if (t >= T_) return;
    const float* w = lin2_w + (size_t)t * COMW;
    const float* c = com + (size_t)b * COMW;
    float s = 0.f;
#pragma unroll
    for (int i = 0; i < 32; i++) {
        int k = lane + 64 * i;
        s += c[k] * w[k];
    }
#pragma unroll
    for (int off = 32; off > 0; off >>= 1) s += __shfl_down(s, off, 64);
    if (lane == 0) out[b * T_ + t] = s + lin2_b[t];
}

// ---------------------------------------------------------------------------
extern "C" void kernel_launch(void* const* d_in, const int* in_sizes, int n_in,
                              void* d_out, int out_size, void* d_ws, size_t ws_size,
                              hipStream_t stream) {
    const int*   context = (const int*)d_in[0];
    const int*   sidx    = (const int*)d_in[1];
    const int*   oidx    = (const int*)d_in[2];
    const int*   sdis    = (const int*)d_in[3];
    const int*   odis    = (const int*)d_in[4];
    const float* etab    = (const float*)d_in[5];
    const float* ptab    = (const float*)d_in[6];
    const float* conv_w  = (const float*)d_in[7];
    const float* conv_b  = (const float*)d_in[8];
    const float* lin1_w  = (const float*)d_in[9];
    const float* lin1_b  = (const float*)d_in[10];
    const float* lin2_w  = (const float*)d_in[11];
    const float* lin2_b  = (const float*)d_in[12];
    float* out = (float*)d_out;

    char* ws = (char*)d_ws;
    size_t off = 0;
    __hip_bfloat16* embp = (__hip_bfloat16*)(ws + off);
    off += (size_t)B_ * LE * E_ * 2;             // 16.9 MB
    off = (off + 255) & ~(size_t)255;
    __hip_bfloat16* posp = (__hip_bfloat16*)(ws + off);
    off += (size_t)B_ * LPP * 128 * 2;           // 8.4 MB
    off = (off + 255) & ~(size_t)255;
    __hip_bfloat16* wce = (__hip_bfloat16*)(ws + off);
    off += (size_t)5 * KOUT * E_ * 2;            // 1.3 MB
    off = (off + 255) & ~(size_t)255;
    __hip_bfloat16* wcp = (__hip_bfloat16*)(ws + off);
    off += (size_t)3 * KOUT * 128 * 2;           // 0.4 MB
    off = (off + 255) & ~(size_t)255;
    float* corr = (float*)(ws + off);
    off += (size_t)B_ * 2 * KOUT * 4;            // 256 KB
    off = (off + 255) & ~(size_t)255;
    unsigned* pooled = (unsigned*)(ws + off);
    off += (size_t)B_ * KOUT * 4;                // 128 KB
    off = (off + 255) & ~(size_t)255;
    float* com = (float*)(ws + off);
    off += (size_t)B_ * COMW * 4;                // 512 KB

    hipMemsetAsync(pooled, 0, (size_t)B_ * KOUT * 4, stream);

    combine_w<<<dim3(3328), dim3(256), 0, stream>>>(conv_w, wce, wcp);
    build_embp<<<dim3(B_ * LE / 4), dim3(256), 0, stream>>>(context, etab, embp);
    build_posp<<<dim3(B_ * LPP / 4), dim3(256), 0, stream>>>(sdis, odis, ptab, posp);
    corr_k<<<dim3(B_, 2), dim3(256), 0, stream>>>(context, etab, conv_w, corr);
    entity_feats<<<dim3(B_, 2), dim3(256), 0, stream>>>(context, sidx, oidx, etab, com);
    conv_gemm_pool<<<dim3(256, 4), dim3(256), 0, stream>>>(embp, posp, wce, wcp, corr, pooled);
    lin1_k<<<dim3(8192), dim3(256), 0, stream>>>(pooled, conv_b, lin1_w, lin1_b, com);
    lin2_k<<<dim3(B_, 14), dim3(256), 0, stream>>>(com, lin2_w, lin2_b, out);
}

// Round 5
// 224.998 us; speedup vs baseline: 2.0239x; 1.2081x over previous
//
#include <hip/hip_runtime.h>
#include <hip/hip_bf16.h>
#include <stdint.h>

#define B_   64
#define L_   512
#define E_   256
#define P_   64
#define KOUT 512
#define KS_  3
#define H_   512
#define T_   53
#define CINW 2688           // conv_w inner: 896*3
#define LE   516            // embp rows/batch: L + 4 (2 zero each side)
#define LPP  514            // posp rows/batch: L + 2 (1 zero each side)
#define COMW 2048           // 1536 ent + 512 sent_h

typedef __attribute__((ext_vector_type(8))) short bf16x8;
typedef __attribute__((ext_vector_type(4))) float f32x4;

__device__ __forceinline__ unsigned enc_f(float x) {
    unsigned u = __float_as_uint(x);
    return (u & 0x80000000u) ? ~u : (u | 0x80000000u);
}
__device__ __forceinline__ float dec_f(unsigned e) {
    return __uint_as_float((e & 0x80000000u) ? (e & 0x7fffffffu) : ~e);
}

__device__ __forceinline__ void cp16(const void* g, void* l) {
    __builtin_amdgcn_global_load_lds(
        (const __attribute__((address_space(1))) unsigned int*)g,
        (__attribute__((address_space(3))) unsigned int*)l,
        16, 0, 0);
}

// ---------------------------------------------------------------------------
// Precombine conv weights. One block per n: conv_w row staged in LDS (read
// exactly once, coalesced), then all derived layouts emitted coalesced.
// wce[d][n][c]  = sum_{seg+tau=d} w[(seg*256+c)*3+tau], d in [0,5)
// wcp[tau][n][p]= w[(768+p)*3+tau]
// wcorr[0][n][c]= w[(512+c)*3+0]   (spurious l=0 term)
// wcorr[1][n][c]= w[c*3+2]         (spurious l=511 term)
__global__ void combine_w(const float* __restrict__ conv_w,
                          __hip_bfloat16* __restrict__ wce,
                          __hip_bfloat16* __restrict__ wcp,
                          __hip_bfloat16* __restrict__ wcorr) {
    __shared__ float w[CINW];           // 10.5 KB
    int n = blockIdx.x;
    const float* src = conv_w + (size_t)n * CINW;
    for (int i = threadIdx.x; i < CINW; i += 256) w[i] = src[i];
    __syncthreads();
    for (int i = threadIdx.x; i < 5 * E_; i += 256) {
        int d = i >> 8, c = i & 255;
        float s = 0.f;
#pragma unroll
        for (int tau = 0; tau <= 2; tau++) {
            int seg = d - tau;
            if (seg >= 0 && seg <= 2) s += w[(seg * 256 + c) * 3 + tau];
        }
        wce[((size_t)d * KOUT + n) * E_ + c] = __float2bfloat16(s);
    }
    for (int i = threadIdx.x; i < 3 * 128; i += 256) {
        int tau = i >> 7, p = i & 127;
        wcp[((size_t)tau * KOUT + n) * 128 + p] = __float2bfloat16(w[(768 + p) * 3 + tau]);
    }
    for (int i = threadIdx.x; i < 2 * E_; i += 256) {
        int which = i >> 8, c = i & 255;
        wcorr[((size_t)which * KOUT + n) * E_ + c] =
            __float2bfloat16(which ? w[c * 3 + 2] : w[(512 + c) * 3 + 0]);
    }
}

// ---------------------------------------------------------------------------
// embp (B, LE, E) bf16: row r = emb(r-2) for r in [2, 514), else 0. One wave/row.
__global__ void build_embp(const int* __restrict__ ctx,
                           const float* __restrict__ etab,
                           __hip_bfloat16* __restrict__ embp) {
    int row = blockIdx.x * 4 + (threadIdx.x >> 6);
    if (row >= B_ * LE) return;
    int lane = threadIdx.x & 63;
    int b = row / LE, r = row % LE;
    __hip_bfloat16* out = embp + (size_t)row * E_;
    if (r < 2 || r >= LE - 2) {
        *(ushort4*)(out + lane * 4) = (ushort4){0, 0, 0, 0};
        return;
    }
    int token = ctx[b * L_ + (r - 2)];
    float4 v = *(const float4*)(etab + (size_t)token * E_ + lane * 4);
    union { __hip_bfloat16 h[4]; ushort4 u; } pk;
    pk.h[0] = __float2bfloat16(v.x); pk.h[1] = __float2bfloat16(v.y);
    pk.h[2] = __float2bfloat16(v.z); pk.h[3] = __float2bfloat16(v.w);
    *(ushort4*)(out + lane * 4) = pk.u;
}

// ---------------------------------------------------------------------------
// posp (B, LPP, 128) bf16: row r = [pos_s(r-1), pos_o(r-1)] for r in [1,513), else 0.
__global__ void build_posp(const int* __restrict__ sdis,
                           const int* __restrict__ odis,
                           const float* __restrict__ ptab,
                           __hip_bfloat16* __restrict__ posp) {
    int row = blockIdx.x * 4 + (threadIdx.x >> 6);
    if (row >= B_ * LPP) return;
    int lane = threadIdx.x & 63;
    int b = row / LPP, r = row % LPP;
    __hip_bfloat16* out = posp + (size_t)row * 128;
    if (r < 1 || r >= LPP - 1) {
        *(unsigned*)(out + lane * 2) = 0u;
        return;
    }
    int l = r - 1;
    int which = lane >> 5;
    int i2 = (lane & 31) * 2;
    int t = which ? odis[b * L_ + l] : sdis[b * L_ + l];
    float2 v = *(const float2*)(ptab + (size_t)t * P_ + i2);
    union { __hip_bfloat16 h[2]; unsigned u; } pk;
    pk.h[0] = __float2bfloat16(v.x); pk.h[1] = __float2bfloat16(v.y);
    *(unsigned*)(out + which * 64 + i2) = pk.u;
}

// ---------------------------------------------------------------------------
// Edge-correction: corr[b][which][n] = emb_edge(b,which) . wcorr[which][n][:]
// One wave per (b, which, 4-n group); lanes cover c -> fully coalesced.
__global__ void corr_k(const int* __restrict__ ctx,
                       const float* __restrict__ etab,
                       const __hip_bfloat16* __restrict__ wcorr,
                       float* __restrict__ corr) {
    int wid = blockIdx.x * 4 + (threadIdx.x >> 6);   // 0..16383
    int lane = threadIdx.x & 63;
    int n4    = wid & 127;
    int which = (wid >> 7) & 1;
    int b     = wid >> 8;
    int token = ctx[b * L_ + (which ? L_ - 1 : 0)];
    float4 ev = *(const float4*)(etab + (size_t)token * E_ + lane * 4);
#pragma unroll
    for (int k = 0; k < 4; k++) {
        int n = n4 * 4 + k;
        const __hip_bfloat16* wr = wcorr + ((size_t)which * KOUT + n) * E_ + lane * 4;
        float s = ev.x * __bfloat162float(wr[0]) + ev.y * __bfloat162float(wr[1])
                + ev.z * __bfloat162float(wr[2]) + ev.w * __bfloat162float(wr[3]);
#pragma unroll
        for (int off = 32; off > 0; off >>= 1) s += __shfl_down(s, off, 64);
        if (lane == 0) corr[(b * 2 + which) * KOUT + n] = s;
    }
}

// ---------------------------------------------------------------------------
// Entity span features -> com rows [0,1536)
__global__ void entity_feats(const int* __restrict__ context,
                             const int* __restrict__ sidx,
                             const int* __restrict__ oidx,
                             const float* __restrict__ etab,
                             float* __restrict__ com) {
    int b = blockIdx.x;
    int which = blockIdx.y;
    const int* idx = which ? oidx : sidx;
    int s = idx[b * 2 + 0], e = idx[b * 2 + 1];
    const int* ctx = context + b * L_;
    float* outb = com + (size_t)b * COMW + which * 768;
    int d = threadIdx.x;
    float sum = 0.f;
    for (int x = s; x <= e; ++x) sum += etab[(size_t)ctx[x] * E_ + d];
    outb[d] = sum / (float)(e - s + 1);
    outb[256 + d] = etab[(size_t)ctx[s - 1] * E_ + d];
    float r = 0.f;
    if (e + 1 < L_) r = etab[(size_t)ctx[e + 1] * E_ + d];
    outb[512 + d] = r;
}

// ---------------------------------------------------------------------------
// conv as 5 emb-taps + 3 pos-taps GEMM (bf16 MFMA), fused maxpool + edge corr.
__global__ void conv_gemm_pool(const __hip_bfloat16* __restrict__ embp,
                               const __hip_bfloat16* __restrict__ posp,
                               const __hip_bfloat16* __restrict__ wce,
                               const __hip_bfloat16* __restrict__ wcp,
                               const float* __restrict__ corr,
                               unsigned* __restrict__ pooled) {
    __shared__ __hip_bfloat16 sA[128 * 32];
    __shared__ __hip_bfloat16 sB[128 * 32];

    const int tid  = threadIdx.x;
    const int wave = tid >> 6;
    const int lane = tid & 63;
    const int mt = blockIdx.x;
    const int nt = blockIdx.y;
    const int b  = mt >> 2;
    const int l0 = (mt & 3) * 128;
    const int n0 = nt * 128;

    const int wr = (wave & 1) * 64;
    const int wc = (wave >> 1) * 64;
    const int m  = lane & 15;
    const int q  = lane >> 4;

    f32x4 acc[4][4];
#pragma unroll
    for (int i = 0; i < 4; i++)
#pragma unroll
        for (int j = 0; j < 4; j++) acc[i][j] = (f32x4){0.f, 0.f, 0.f, 0.f};

    const int rowA = tid >> 2;
    const int cswz = (((tid & 3) ^ ((tid >> 3) & 3))) * 16;
    const int rsw  = (q ^ ((m >> 1) & 3)) * 16;

    auto step = [&](const char* Ab, int AsB, const char* Bb, int BsB) {
        cp16(Ab + rowA * AsB + cswz, (char*)sA + tid * 16);
        cp16(Bb + rowA * BsB + cswz, (char*)sB + tid * 16);
        cp16(Ab + (rowA + 64) * AsB + cswz, (char*)sA + (tid + 256) * 16);
        cp16(Bb + (rowA + 64) * BsB + cswz, (char*)sB + (tid + 256) * 16);
        __syncthreads();
        bf16x8 af[4], bfr[4];
#pragma unroll
        for (int i = 0; i < 4; i++)
            af[i] = *(const bf16x8*)((const char*)sA + (wr + i * 16 + m) * 64 + rsw);
#pragma unroll
        for (int j = 0; j < 4; j++)
            bfr[j] = *(const bf16x8*)((const char*)sB + (wc + j * 16 + m) * 64 + rsw);
#pragma unroll
        for (int i = 0; i < 4; i++)
#pragma unroll
            for (int j = 0; j < 4; j++)
                acc[i][j] = __builtin_amdgcn_mfma_f32_16x16x32_bf16(
                    af[i], bfr[j], acc[i][j], 0, 0, 0);
        __syncthreads();
    };

    for (int t = 0; t < 5; t++) {
        const char* Abase = (const char*)(embp + (size_t)(b * LE + l0 + t) * E_);
        const char* Bbase = (const char*)(wce + (size_t)(t * KOUT + n0) * E_);
        for (int kc = 0; kc < E_; kc += 32)
            step(Abase + kc * 2, E_ * 2, Bbase + kc * 2, E_ * 2);
    }
    for (int t = 0; t < 3; t++) {
        const char* Abase = (const char*)(posp + (size_t)(b * LPP + l0 + t) * 128);
        const char* Bbase = (const char*)(wcp + (size_t)(t * KOUT + n0) * 128);
        for (int kc = 0; kc < 128; kc += 32)
            step(Abase + kc * 2, 256, Bbase + kc * 2, 256);
    }

    const float* corrb = corr + b * 2 * KOUT;
#pragma unroll
    for (int j = 0; j < 4; j++) {
        int col = n0 + wc + j * 16 + m;
        float mx = -3.4e38f;
#pragma unroll
        for (int i = 0; i < 4; i++)
#pragma unroll
            for (int r = 0; r < 4; r++) {
                float v = acc[i][j][r];
                int l = l0 + wr + i * 16 + q * 4 + r;
                if (l == 0)      v -= corrb[col];
                if (l == L_ - 1) v -= corrb[KOUT + col];
                mx = fmaxf(mx, v);
            }
        mx = fmaxf(mx, __shfl_xor(mx, 16, 64));
        mx = fmaxf(mx, __shfl_xor(mx, 32, 64));
        if (q == 0) atomicMax(&pooled[b * KOUT + col], enc_f(mx));
    }
}

// ---------------------------------------------------------------------------
__global__ void lin1_k(const unsigned* __restrict__ pooled,
                       const float* __restrict__ conv_b,
                       const float* __restrict__ lin1_w,
                       const float* __restrict__ lin1_b,
                       float* __restrict__ com) {
    int bid = blockIdx.x;
    int wave = threadIdx.x >> 6, lane = threadIdx.x & 63;
    int b = bid >> 7;
    int h = (bid & 127) * 4 + wave;
    const float* w = lin1_w + (size_t)h * KOUT;
    const unsigned* pb = pooled + b * KOUT;
    float s = 0.f;
#pragma unroll
    for (int i = 0; i < 8; i++) {
        int k = lane + 64 * i;
        s += (dec_f(pb[k]) + conv_b[k]) * w[k];
    }
#pragma unroll
    for (int off = 32; off > 0; off >>= 1) s += __shfl_down(s, off, 64);
    if (lane == 0) com[(size_t)b * COMW + 1536 + h] = tanhf(s + lin1_b[h]);
}

__global__ void lin2_k(const float* __restrict__ com,
                       const float* __restrict__ lin2_w,
                       const float* __restrict__ lin2_b,
                       float* __restrict__ out) {
    int b = blockIdx.x;
    int wave = threadIdx.x >> 6, lane = threadIdx.x & 63;
    int t = blockIdx.y * 4 + wave;
    if (t >= T_) return;
    const float* w = lin2_w + (size_t)t * COMW;
    const float* c = com + (size_t)b * COMW;
    float s = 0.f;
#pragma unroll
    for (int i = 0; i < 32; i++) {
        int k = lane + 64 * i;
        s += c[k] * w[k];
    }
#pragma unroll
    for (int off = 32; off > 0; off >>= 1) s += __shfl_down(s, off, 64);
    if (lane == 0) out[b * T_ + t] = s + lin2_b[t];
}

// ---------------------------------------------------------------------------
extern "C" void kernel_launch(void* const* d_in, const int* in_sizes, int n_in,
                              void* d_out, int out_size, void* d_ws, size_t ws_size,
                              hipStream_t stream) {
    const int*   context = (const int*)d_in[0];
    const int*   sidx    = (const int*)d_in[1];
    const int*   oidx    = (const int*)d_in[2];
    const int*   sdis    = (const int*)d_in[3];
    const int*   odis    = (const int*)d_in[4];
    const float* etab    = (const float*)d_in[5];
    const float* ptab    = (const float*)d_in[6];
    const float* conv_w  = (const float*)d_in[7];
    const float* conv_b  = (const float*)d_in[8];
    const float* lin1_w  = (const float*)d_in[9];
    const float* lin1_b  = (const float*)d_in[10];
    const float* lin2_w  = (const float*)d_in[11];
    const float* lin2_b  = (const float*)d_in[12];
    float* out = (float*)d_out;

    char* ws = (char*)d_ws;
    size_t off = 0;
    __hip_bfloat16* embp = (__hip_bfloat16*)(ws + off);
    off += (size_t)B_ * LE * E_ * 2;             // 16.9 MB
    off = (off + 255) & ~(size_t)255;
    __hip_bfloat16* posp = (__hip_bfloat16*)(ws + off);
    off += (size_t)B_ * LPP * 128 * 2;           // 8.4 MB
    off = (off + 255) & ~(size_t)255;
    __hip_bfloat16* wce = (__hip_bfloat16*)(ws + off);
    off += (size_t)5 * KOUT * E_ * 2;            // 1.3 MB
    off = (off + 255) & ~(size_t)255;
    __hip_bfloat16* wcp = (__hip_bfloat16*)(ws + off);
    off += (size_t)3 * KOUT * 128 * 2;           // 0.4 MB
    off = (off + 255) & ~(size_t)255;
    __hip_bfloat16* wcorr = (__hip_bfloat16*)(ws + off);
    off += (size_t)2 * KOUT * E_ * 2;            // 0.5 MB
    off = (off + 255) & ~(size_t)255;
    float* corr = (float*)(ws + off);
    off += (size_t)B_ * 2 * KOUT * 4;            // 256 KB
    off = (off + 255) & ~(size_t)255;
    unsigned* pooled = (unsigned*)(ws + off);
    off += (size_t)B_ * KOUT * 4;                // 128 KB
    off = (off + 255) & ~(size_t)255;
    float* com = (float*)(ws + off);
    off += (size_t)B_ * COMW * 4;                // 512 KB

    hipMemsetAsync(pooled, 0, (size_t)B_ * KOUT * 4, stream);

    combine_w<<<dim3(512), dim3(256), 0, stream>>>(conv_w, wce, wcp, wcorr);
    build_embp<<<dim3(B_ * LE / 4), dim3(256), 0, stream>>>(context, etab, embp);
    build_posp<<<dim3(B_ * LPP / 4), dim3(256), 0, stream>>>(sdis, odis, ptab, posp);
    corr_k<<<dim3(4096), dim3(256), 0, stream>>>(context, etab, wcorr, corr);
    entity_feats<<<dim3(B_, 2), dim3(256), 0, stream>>>(context, sidx, oidx, etab, com);
    conv_gemm_pool<<<dim3(256, 4), dim3(256), 0, stream>>>(embp, posp, wce, wcp, corr, pooled);
    lin1_k<<<dim3(8192), dim3(256), 0, stream>>>(pooled, conv_b, lin1_w, lin1_b, com);
    lin2_k<<<dim3(B_, 14), dim3(256), 0, stream>>>(com, lin2_w, lin2_b, out);
}

// Round 6
// 214.381 us; speedup vs baseline: 2.1242x; 1.0495x over previous
//
#include <hip/hip_runtime.h>
#include <hip/hip_bf16.h>
#include <stdint.h>

#define B_   64
#define L_   512
#define E_   256
#define P_   64
#define KOUT 512
#define KS_  3
#define H_   512
#define T_   53
#define CINW 2688           // conv_w inner: 896*3
#define LE   516            // embp rows/batch: L + 4 (2 zero each side)
#define LPP  514            // posp rows/batch: L + 2 (1 zero each side)
#define COMW 2048           // 1536 ent + 512 sent_h

// prep-kernel grid sections
#define SEC_CW    0
#define SEC_EMBP  512
#define SEC_POSP  (SEC_EMBP + (B_ * LE / 4))     // 512 + 8256 = 8768
#define SEC_ENT   (SEC_POSP + (B_ * LPP / 4))    // 8768 + 8224 = 16992
#define SEC_POOL  (SEC_ENT + 2 * B_)             // 16992 + 128 = 17120
#define SEC_END   (SEC_POOL + 32)                // 17152

typedef __attribute__((ext_vector_type(8))) short bf16x8;
typedef __attribute__((ext_vector_type(4))) float f32x4;

__device__ __forceinline__ unsigned enc_f(float x) {
    unsigned u = __float_as_uint(x);
    return (u & 0x80000000u) ? ~u : (u | 0x80000000u);
}
__device__ __forceinline__ float dec_f(unsigned e) {
    return __uint_as_float((e & 0x80000000u) ? (e & 0x7fffffffu) : ~e);
}

__device__ __forceinline__ void cp16(const void* g, void* l) {
    __builtin_amdgcn_global_load_lds(
        (const __attribute__((address_space(1))) unsigned int*)g,
        (__attribute__((address_space(3))) unsigned int*)l,
        16, 0, 0);
}

// ---------------------------------------------------------------------------
// Fused prep: 5 independent jobs selected by blockIdx.x section.
//  [0,512):        combine_w (per-n weight repack -> wce/wcp/wcorr)
//  [512,8768):     build_embp
//  [8768,16992):   build_posp
//  [16992,17120):  entity_feats -> com[:,0:1536)
//  [17120,17152):  zero pooled
__global__ void prep(const float* __restrict__ conv_w,
                     const int* __restrict__ context,
                     const int* __restrict__ sidx,
                     const int* __restrict__ oidx,
                     const int* __restrict__ sdis,
                     const int* __restrict__ odis,
                     const float* __restrict__ etab,
                     const float* __restrict__ ptab,
                     __hip_bfloat16* __restrict__ wce,
                     __hip_bfloat16* __restrict__ wcp,
                     __hip_bfloat16* __restrict__ wcorr,
                     __hip_bfloat16* __restrict__ embp,
                     __hip_bfloat16* __restrict__ posp,
                     float* __restrict__ com,
                     unsigned* __restrict__ pooled) {
    __shared__ float w[CINW];           // used by combine_w section only
    const int blk = blockIdx.x;
    const int tid = threadIdx.x;

    if (blk < SEC_EMBP) {
        // ---- combine_w: one block per output channel n ----
        int n = blk;
        const float* src = conv_w + (size_t)n * CINW;
        for (int i = tid; i < CINW; i += 256) w[i] = src[i];
        __syncthreads();
        for (int i = tid; i < 5 * E_; i += 256) {
            int d = i >> 8, c = i & 255;
            float s = 0.f;
#pragma unroll
            for (int tau = 0; tau <= 2; tau++) {
                int seg = d - tau;
                if (seg >= 0 && seg <= 2) s += w[(seg * 256 + c) * 3 + tau];
            }
            wce[((size_t)d * KOUT + n) * E_ + c] = __float2bfloat16(s);
        }
        for (int i = tid; i < 3 * 128; i += 256) {
            int tau = i >> 7, p = i & 127;
            wcp[((size_t)tau * KOUT + n) * 128 + p] = __float2bfloat16(w[(768 + p) * 3 + tau]);
        }
        for (int i = tid; i < 2 * E_; i += 256) {
            int which = i >> 8, c = i & 255;
            wcorr[((size_t)which * KOUT + n) * E_ + c] =
                __float2bfloat16(which ? w[c * 3 + 2] : w[(512 + c) * 3 + 0]);
        }
    } else if (blk < SEC_POSP) {
        // ---- build_embp: 4 rows per block, one wave per row ----
        int row = (blk - SEC_EMBP) * 4 + (tid >> 6);
        int lane = tid & 63;
        int b = row / LE, r = row % LE;
        __hip_bfloat16* out = embp + (size_t)row * E_;
        if (r < 2 || r >= LE - 2) {
            *(ushort4*)(out + lane * 4) = (ushort4){0, 0, 0, 0};
            return;
        }
        int token = context[b * L_ + (r - 2)];
        float4 v = *(const float4*)(etab + (size_t)token * E_ + lane * 4);
        union { __hip_bfloat16 h[4]; ushort4 u; } pk;
        pk.h[0] = __float2bfloat16(v.x); pk.h[1] = __float2bfloat16(v.y);
        pk.h[2] = __float2bfloat16(v.z); pk.h[3] = __float2bfloat16(v.w);
        *(ushort4*)(out + lane * 4) = pk.u;
    } else if (blk < SEC_ENT) {
        // ---- build_posp: 4 rows per block, one wave per row ----
        int row = (blk - SEC_POSP) * 4 + (tid >> 6);
        int lane = tid & 63;
        int b = row / LPP, r = row % LPP;
        __hip_bfloat16* out = posp + (size_t)row * 128;
        if (r < 1 || r >= LPP - 1) {
            *(unsigned*)(out + lane * 2) = 0u;
            return;
        }
        int l = r - 1;
        int which = lane >> 5;
        int i2 = (lane & 31) * 2;
        int t = which ? odis[b * L_ + l] : sdis[b * L_ + l];
        float2 v = *(const float2*)(ptab + (size_t)t * P_ + i2);
        union { __hip_bfloat16 h[2]; unsigned u; } pk;
        pk.h[0] = __float2bfloat16(v.x); pk.h[1] = __float2bfloat16(v.y);
        *(unsigned*)(out + which * 64 + i2) = pk.u;
    } else if (blk < SEC_POOL) {
        // ---- entity_feats ----
        int idx = blk - SEC_ENT;
        int b = idx >> 1, which = idx & 1;
        const int* sp = which ? oidx : sidx;
        int s = sp[b * 2 + 0], e = sp[b * 2 + 1];
        const int* ctx = context + b * L_;
        float* outb = com + (size_t)b * COMW + which * 768;
        int d = tid;                    // 256 == E_
        float sum = 0.f;
        for (int x = s; x <= e; ++x) sum += etab[(size_t)ctx[x] * E_ + d];
        outb[d] = sum / (float)(e - s + 1);
        outb[256 + d] = etab[(size_t)ctx[s - 1] * E_ + d];
        float r = 0.f;
        if (e + 1 < L_) r = etab[(size_t)ctx[e + 1] * E_ + d];
        outb[512 + d] = r;
    } else {
        // ---- zero pooled: 32 blocks x 256 threads x 4 uints = 32768 ----
        int base = ((blk - SEC_POOL) * 256 + tid) * 4;
        *(uint4*)(pooled + base) = (uint4){0, 0, 0, 0};
    }
}

// ---------------------------------------------------------------------------
// Edge-correction: corr[b][which][n] = emb_edge(b,which) . wcorr[which][n][:]
__global__ void corr_k(const int* __restrict__ ctx,
                       const float* __restrict__ etab,
                       const __hip_bfloat16* __restrict__ wcorr,
                       float* __restrict__ corr) {
    int wid = blockIdx.x * 4 + (threadIdx.x >> 6);   // 0..16383
    int lane = threadIdx.x & 63;
    int n4    = wid & 127;
    int which = (wid >> 7) & 1;
    int b     = wid >> 8;
    int token = ctx[b * L_ + (which ? L_ - 1 : 0)];
    float4 ev = *(const float4*)(etab + (size_t)token * E_ + lane * 4);
#pragma unroll
    for (int k = 0; k < 4; k++) {
        int n = n4 * 4 + k;
        const __hip_bfloat16* wr = wcorr + ((size_t)which * KOUT + n) * E_ + lane * 4;
        float s = ev.x * __bfloat162float(wr[0]) + ev.y * __bfloat162float(wr[1])
                + ev.z * __bfloat162float(wr[2]) + ev.w * __bfloat162float(wr[3]);
#pragma unroll
        for (int off = 32; off > 0; off >>= 1) s += __shfl_down(s, off, 64);
        if (lane == 0) corr[(b * 2 + which) * KOUT + n] = s;
    }
}

// ---------------------------------------------------------------------------
// conv as 5 emb-taps + 3 pos-taps GEMM (bf16 MFMA), fused maxpool + edge corr.
__global__ void conv_gemm_pool(const __hip_bfloat16* __restrict__ embp,
                               const __hip_bfloat16* __restrict__ posp,
                               const __hip_bfloat16* __restrict__ wce,
                               const __hip_bfloat16* __restrict__ wcp,
                               const float* __restrict__ corr,
                               unsigned* __restrict__ pooled) {
    __shared__ __hip_bfloat16 sA[128 * 32];
    __shared__ __hip_bfloat16 sB[128 * 32];

    const int tid  = threadIdx.x;
    const int wave = tid >> 6;
    const int lane = tid & 63;
    const int mt = blockIdx.x;
    const int nt = blockIdx.y;
    const int b  = mt >> 2;
    const int l0 = (mt & 3) * 128;
    const int n0 = nt * 128;

    const int wr = (wave & 1) * 64;
    const int wc = (wave >> 1) * 64;
    const int m  = lane & 15;
    const int q  = lane >> 4;

    f32x4 acc[4][4];
#pragma unroll
    for (int i = 0; i < 4; i++)
#pragma unroll
        for (int j = 0; j < 4; j++) acc[i][j] = (f32x4){0.f, 0.f, 0.f, 0.f};

    const int rowA = tid >> 2;
    const int cswz = (((tid & 3) ^ ((tid >> 3) & 3))) * 16;
    const int rsw  = (q ^ ((m >> 1) & 3)) * 16;

    auto step = [&](const char* Ab, int AsB, const char* Bb, int BsB) {
        cp16(Ab + rowA * AsB + cswz, (char*)sA + tid * 16);
        cp16(Bb + rowA * BsB + cswz, (char*)sB + tid * 16);
        cp16(Ab + (rowA + 64) * AsB + cswz, (char*)sA + (tid + 256) * 16);
        cp16(Bb + (rowA + 64) * BsB + cswz, (char*)sB + (tid + 256) * 16);
        __syncthreads();
        bf16x8 af[4], bfr[4];
#pragma unroll
        for (int i = 0; i < 4; i++)
            af[i] = *(const bf16x8*)((const char*)sA + (wr + i * 16 + m) * 64 + rsw);
#pragma unroll
        for (int j = 0; j < 4; j++)
            bfr[j] = *(const bf16x8*)((const char*)sB + (wc + j * 16 + m) * 64 + rsw);
#pragma unroll
        for (int i = 0; i < 4; i++)
#pragma unroll
            for (int j = 0; j < 4; j++)
                acc[i][j] = __builtin_amdgcn_mfma_f32_16x16x32_bf16(
                    af[i], bfr[j], acc[i][j], 0, 0, 0);
        __syncthreads();
    };

    for (int t = 0; t < 5; t++) {
        const char* Abase = (const char*)(embp + (size_t)(b * LE + l0 + t) * E_);
        const char* Bbase = (const char*)(wce + (size_t)(t * KOUT + n0) * E_);
        for (int kc = 0; kc < E_; kc += 32)
            step(Abase + kc * 2, E_ * 2, Bbase + kc * 2, E_ * 2);
    }
    for (int t = 0; t < 3; t++) {
        const char* Abase = (const char*)(posp + (size_t)(b * LPP + l0 + t) * 128);
        const char* Bbase = (const char*)(wcp + (size_t)(t * KOUT + n0) * 128);
        for (int kc = 0; kc < 128; kc += 32)
            step(Abase + kc * 2, 256, Bbase + kc * 2, 256);
    }

    const float* corrb = corr + b * 2 * KOUT;
#pragma unroll
    for (int j = 0; j < 4; j++) {
        int col = n0 + wc + j * 16 + m;
        float mx = -3.4e38f;
#pragma unroll
        for (int i = 0; i < 4; i++)
#pragma unroll
            for (int r = 0; r < 4; r++) {
                float v = acc[i][j][r];
                int l = l0 + wr + i * 16 + q * 4 + r;
                if (l == 0)      v -= corrb[col];
                if (l == L_ - 1) v -= corrb[KOUT + col];
                mx = fmaxf(mx, v);
            }
        mx = fmaxf(mx, __shfl_xor(mx, 16, 64));
        mx = fmaxf(mx, __shfl_xor(mx, 32, 64));
        if (q == 0) atomicMax(&pooled[b * KOUT + col], enc_f(mx));
    }
}

// ---------------------------------------------------------------------------
__global__ void lin1_k(const unsigned* __restrict__ pooled,
                       const float* __restrict__ conv_b,
                       const float* __restrict__ lin1_w,
                       const float* __restrict__ lin1_b,
                       float* __restrict__ com) {
    int bid = blockIdx.x;
    int wave = threadIdx.x >> 6, lane = threadIdx.x & 63;
    int b = bid >> 7;
    int h = (bid & 127) * 4 + wave;
    const float* w = lin1_w + (size_t)h * KOUT;
    const unsigned* pb = pooled + b * KOUT;
    float s = 0.f;
#pragma unroll
    for (int i = 0; i < 8; i++) {
        int k = lane + 64 * i;
        s += (dec_f(pb[k]) + conv_b[k]) * w[k];
    }
#pragma unroll
    for (int off = 32; off > 0; off >>= 1) s += __shfl_down(s, off, 64);
    if (lane == 0) com[(size_t)b * COMW + 1536 + h] = tanhf(s + lin1_b[h]);
}

__global__ void lin2_k(const float* __restrict__ com,
                       const float* __restrict__ lin2_w,
                       const float* __restrict__ lin2_b,
                       float* __restrict__ out) {
    int b = blockIdx.x;
    int wave = threadIdx.x >> 6, lane = threadIdx.x & 63;
    int t = blockIdx.y * 4 + wave;
    if (t >= T_) return;
    const float* w = lin2_w + (size_t)t * COMW;
    const float* c = com + (size_t)b * COMW;
    float s = 0.f;
#pragma unroll
    for (int i = 0; i < 32; i++) {
        int k = lane + 64 * i;
        s += c[k] * w[k];
    }
#pragma unroll
    for (int off = 32; off > 0; off >>= 1) s += __shfl_down(s, off, 64);
    if (lane == 0) out[b * T_ + t] = s + lin2_b[t];
}

// ---------------------------------------------------------------------------
extern "C" void kernel_launch(void* const* d_in, const int* in_sizes, int n_in,
                              void* d_out, int out_size, void* d_ws, size_t ws_size,
                              hipStream_t stream) {
    const int*   context = (const int*)d_in[0];
    const int*   sidx    = (const int*)d_in[1];
    const int*   oidx    = (const int*)d_in[2];
    const int*   sdis    = (const int*)d_in[3];
    const int*   odis    = (const int*)d_in[4];
    const float* etab    = (const float*)d_in[5];
    const float* ptab    = (const float*)d_in[6];
    const float* conv_w  = (const float*)d_in[7];
    const float* conv_b  = (const float*)d_in[8];
    const float* lin1_w  = (const float*)d_in[9];
    const float* lin1_b  = (const float*)d_in[10];
    const float* lin2_w  = (const float*)d_in[11];
    const float* lin2_b  = (const float*)d_in[12];
    float* out = (float*)d_out;

    char* ws = (char*)d_ws;
    size_t off = 0;
    __hip_bfloat16* embp = (__hip_bfloat16*)(ws + off);
    off += (size_t)B_ * LE * E_ * 2;             // 16.9 MB
    off = (off + 255) & ~(size_t)255;
    __hip_bfloat16* posp = (__hip_bfloat16*)(ws + off);
    off += (size_t)B_ * LPP * 128 * 2;           // 8.4 MB
    off = (off + 255) & ~(size_t)255;
    __hip_bfloat16* wce = (__hip_bfloat16*)(ws + off);
    off += (size_t)5 * KOUT * E_ * 2;            // 1.3 MB
    off = (off + 255) & ~(size_t)255;
    __hip_bfloat16* wcp = (__hip_bfloat16*)(ws + off);
    off += (size_t)3 * KOUT * 128 * 2;           // 0.4 MB
    off = (off + 255) & ~(size_t)255;
    __hip_bfloat16* wcorr = (__hip_bfloat16*)(ws + off);
    off += (size_t)2 * KOUT * E_ * 2;            // 0.5 MB
    off = (off + 255) & ~(size_t)255;
    float* corr = (float*)(ws + off);
    off += (size_t)B_ * 2 * KOUT * 4;            // 256 KB
    off = (off + 255) & ~(size_t)255;
    unsigned* pooled = (unsigned*)(ws + off);
    off += (size_t)B_ * KOUT * 4;                // 128 KB
    off = (off + 255) & ~(size_t)255;
    float* com = (float*)(ws + off);
    off += (size_t)B_ * COMW * 4;                // 512 KB

    prep<<<dim3(SEC_END), dim3(256), 0, stream>>>(
        conv_w, context, sidx, oidx, sdis, odis, etab, ptab,
        wce, wcp, wcorr, embp, posp, com, pooled);
    corr_k<<<dim3(4096), dim3(256), 0, stream>>>(context, etab, wcorr, corr);
    conv_gemm_pool<<<dim3(256, 4), dim3(256), 0, stream>>>(embp, posp, wce, wcp, corr, pooled);
    lin1_k<<<dim3(8192), dim3(256), 0, stream>>>(pooled, conv_b, lin1_w, lin1_b, com);
    lin2_k<<<dim3(B_, 14), dim3(256), 0, stream>>>(com, lin2_w, lin2_b, out);
}

// Round 7
// 212.992 us; speedup vs baseline: 2.1380x; 1.0065x over previous
//
#include <hip/hip_runtime.h>
#include <hip/hip_bf16.h>
#include <stdint.h>

#define B_   64
#define L_   512
#define E_   256
#define P_   64
#define KOUT 512
#define KS_  3
#define H_   512
#define T_   53
#define CINW 2688           // conv_w inner: 896*3
#define LE   516            // embp rows/batch: L + 4 (2 zero each side)
#define LPP  514            // posp rows/batch: L + 2 (1 zero each side)
#define COMW 2048           // 1536 ent + 512 sent_h

// prep-kernel grid sections
#define SEC_CW    0
#define SEC_EMBP  512
#define SEC_POSP  (SEC_EMBP + (B_ * LE / 4))     // 512 + 8256 = 8768
#define SEC_ENT   (SEC_POSP + (B_ * LPP / 4))    // 8768 + 8224 = 16992
#define SEC_POOL  (SEC_ENT + 2 * B_)             // 16992 + 128 = 17120
#define SEC_END   (SEC_POOL + 32)                // 17152

typedef __attribute__((ext_vector_type(8))) short bf16x8;
typedef __attribute__((ext_vector_type(4))) float f32x4;

__device__ __forceinline__ unsigned enc_f(float x) {
    unsigned u = __float_as_uint(x);
    return (u & 0x80000000u) ? ~u : (u | 0x80000000u);
}
__device__ __forceinline__ float dec_f(unsigned e) {
    return __uint_as_float((e & 0x80000000u) ? (e & 0x7fffffffu) : ~e);
}

__device__ __forceinline__ void cp16(const void* g, void* l) {
    __builtin_amdgcn_global_load_lds(
        (const __attribute__((address_space(1))) unsigned int*)g,
        (__attribute__((address_space(3))) unsigned int*)l,
        16, 0, 0);
}

// ---------------------------------------------------------------------------
// Fused prep: 5 independent jobs selected by blockIdx.x section.
__global__ void prep(const float* __restrict__ conv_w,
                     const int* __restrict__ context,
                     const int* __restrict__ sidx,
                     const int* __restrict__ oidx,
                     const int* __restrict__ sdis,
                     const int* __restrict__ odis,
                     const float* __restrict__ etab,
                     const float* __restrict__ ptab,
                     __hip_bfloat16* __restrict__ wce,
                     __hip_bfloat16* __restrict__ wcp,
                     __hip_bfloat16* __restrict__ wcorr,
                     __hip_bfloat16* __restrict__ embp,
                     __hip_bfloat16* __restrict__ posp,
                     float* __restrict__ com,
                     unsigned* __restrict__ pooled) {
    __shared__ float w[CINW];           // used by combine_w section only
    const int blk = blockIdx.x;
    const int tid = threadIdx.x;

    if (blk < SEC_EMBP) {
        // ---- combine_w: one block per output channel n ----
        int n = blk;
        const float* src = conv_w + (size_t)n * CINW;
        for (int i = tid; i < CINW; i += 256) w[i] = src[i];
        __syncthreads();
        for (int i = tid; i < 5 * E_; i += 256) {
            int d = i >> 8, c = i & 255;
            float s = 0.f;
#pragma unroll
            for (int tau = 0; tau <= 2; tau++) {
                int seg = d - tau;
                if (seg >= 0 && seg <= 2) s += w[(seg * 256 + c) * 3 + tau];
            }
            wce[((size_t)d * KOUT + n) * E_ + c] = __float2bfloat16(s);
        }
        for (int i = tid; i < 3 * 128; i += 256) {
            int tau = i >> 7, p = i & 127;
            wcp[((size_t)tau * KOUT + n) * 128 + p] = __float2bfloat16(w[(768 + p) * 3 + tau]);
        }
        for (int i = tid; i < 2 * E_; i += 256) {
            int which = i >> 8, c = i & 255;
            wcorr[((size_t)which * KOUT + n) * E_ + c] =
                __float2bfloat16(which ? w[c * 3 + 2] : w[(512 + c) * 3 + 0]);
        }
    } else if (blk < SEC_POSP) {
        // ---- build_embp ----
        int row = (blk - SEC_EMBP) * 4 + (tid >> 6);
        int lane = tid & 63;
        int b = row / LE, r = row % LE;
        __hip_bfloat16* out = embp + (size_t)row * E_;
        if (r < 2 || r >= LE - 2) {
            *(ushort4*)(out + lane * 4) = (ushort4){0, 0, 0, 0};
            return;
        }
        int token = context[b * L_ + (r - 2)];
        float4 v = *(const float4*)(etab + (size_t)token * E_ + lane * 4);
        union { __hip_bfloat16 h[4]; ushort4 u; } pk;
        pk.h[0] = __float2bfloat16(v.x); pk.h[1] = __float2bfloat16(v.y);
        pk.h[2] = __float2bfloat16(v.z); pk.h[3] = __float2bfloat16(v.w);
        *(ushort4*)(out + lane * 4) = pk.u;
    } else if (blk < SEC_ENT) {
        // ---- build_posp ----
        int row = (blk - SEC_POSP) * 4 + (tid >> 6);
        int lane = tid & 63;
        int b = row / LPP, r = row % LPP;
        __hip_bfloat16* out = posp + (size_t)row * 128;
        if (r < 1 || r >= LPP - 1) {
            *(unsigned*)(out + lane * 2) = 0u;
            return;
        }
        int l = r - 1;
        int which = lane >> 5;
        int i2 = (lane & 31) * 2;
        int t = which ? odis[b * L_ + l] : sdis[b * L_ + l];
        float2 v = *(const float2*)(ptab + (size_t)t * P_ + i2);
        union { __hip_bfloat16 h[2]; unsigned u; } pk;
        pk.h[0] = __float2bfloat16(v.x); pk.h[1] = __float2bfloat16(v.y);
        *(unsigned*)(out + which * 64 + i2) = pk.u;
    } else if (blk < SEC_POOL) {
        // ---- entity_feats ----
        int idx = blk - SEC_ENT;
        int b = idx >> 1, which = idx & 1;
        const int* sp = which ? oidx : sidx;
        int s = sp[b * 2 + 0], e = sp[b * 2 + 1];
        const int* ctx = context + b * L_;
        float* outb = com + (size_t)b * COMW + which * 768;
        int d = tid;
        float sum = 0.f;
        for (int x = s; x <= e; ++x) sum += etab[(size_t)ctx[x] * E_ + d];
        outb[d] = sum / (float)(e - s + 1);
        outb[256 + d] = etab[(size_t)ctx[s - 1] * E_ + d];
        float r = 0.f;
        if (e + 1 < L_) r = etab[(size_t)ctx[e + 1] * E_ + d];
        outb[512 + d] = r;
    } else {
        // ---- zero pooled ----
        int base = ((blk - SEC_POOL) * 256 + tid) * 4;
        *(uint4*)(pooled + base) = (uint4){0, 0, 0, 0};
    }
}

// ---------------------------------------------------------------------------
// Edge-correction: corr[b][which][n] = emb_edge(b,which) . wcorr[which][n][:]
__global__ void corr_k(const int* __restrict__ ctx,
                       const float* __restrict__ etab,
                       const __hip_bfloat16* __restrict__ wcorr,
                       float* __restrict__ corr) {
    int wid = blockIdx.x * 4 + (threadIdx.x >> 6);
    int lane = threadIdx.x & 63;
    int n4    = wid & 127;
    int which = (wid >> 7) & 1;
    int b     = wid >> 8;
    int token = ctx[b * L_ + (which ? L_ - 1 : 0)];
    float4 ev = *(const float4*)(etab + (size_t)token * E_ + lane * 4);
#pragma unroll
    for (int k = 0; k < 4; k++) {
        int n = n4 * 4 + k;
        const __hip_bfloat16* wr = wcorr + ((size_t)which * KOUT + n) * E_ + lane * 4;
        float s = ev.x * __bfloat162float(wr[0]) + ev.y * __bfloat162float(wr[1])
                + ev.z * __bfloat162float(wr[2]) + ev.w * __bfloat162float(wr[3]);
#pragma unroll
        for (int off = 32; off > 0; off >>= 1) s += __shfl_down(s, off, 64);
        if (lane == 0) corr[(b * 2 + which) * KOUT + n] = s;
    }
}

// ---------------------------------------------------------------------------
// conv GEMM with tap-shift A-reuse: per 32-wide K-chunk, stage ONE A panel
// (132 rows, shared by all 5 emb taps via LDS row offset +t) plus all taps'
// B panels; 80 MFMA/wave between one barrier pair. Barriers 104 -> 24.
// A read swizzle: (q ^ (((m+t)>>1)&3)); B: (q ^ ((m>>1)&3)).
__global__ void conv_gemm_pool(const __hip_bfloat16* __restrict__ embp,
                               const __hip_bfloat16* __restrict__ posp,
                               const __hip_bfloat16* __restrict__ wce,
                               const __hip_bfloat16* __restrict__ wcp,
                               const float* __restrict__ corr,
                               unsigned* __restrict__ pooled) {
    __shared__ __hip_bfloat16 sA[768 * 8];    // 12 KB: 768 slots x 16B (132 rows used)
    __shared__ __hip_bfloat16 sB[2560 * 8];   // 40 KB: 5 taps x 128 rows x 64B

    const int tid  = threadIdx.x;
    const int wave = tid >> 6;
    const int lane = tid & 63;
    const int mt = blockIdx.x;
    const int nt = blockIdx.y;
    const int b  = mt >> 2;
    const int l0 = (mt & 3) * 128;
    const int n0 = nt * 128;

    const int wr = (wave & 1) * 64;
    const int wc = (wave >> 1) * 64;
    const int m  = lane & 15;
    const int q  = lane >> 4;
    const int bsw = (q ^ ((m >> 1) & 3)) * 16;

    f32x4 acc[4][4];
#pragma unroll
    for (int i = 0; i < 4; i++)
#pragma unroll
        for (int j = 0; j < 4; j++) acc[i][j] = (f32x4){0.f, 0.f, 0.f, 0.f};

    // ---- emb phase: 8 K-chunks, 5 taps each ----
    for (int kc = 0; kc < E_; kc += 32) {
        // stage A: rows l0..l0+131 of embp (132 rows x 64B), 3 rounds
#pragma unroll
        for (int r = 0; r < 3; r++) {
            int s = r * 256 + tid;
            int row = s >> 2; if (row > 131) row = 131;   // pad slots: harmless dup
            int c = (s & 3) ^ ((row >> 1) & 3);
            const char* src = (const char*)(embp + (size_t)(b * LE + l0 + row) * E_ + kc) + c * 16;
            cp16(src, (char*)sA + s * 16);
        }
        // stage B: 5 taps x 128 rows x 64B, 10 rounds
#pragma unroll
        for (int r = 0; r < 10; r++) {
            int s = r * 256 + tid;
            int tap = s >> 9;
            int n = (s >> 2) & 127;
            int c = (s & 3) ^ ((n >> 1) & 3);
            const char* src = (const char*)(wce + (size_t)(tap * KOUT + n0 + n) * E_ + kc) + c * 16;
            cp16(src, (char*)sB + s * 16);
        }
        __syncthreads();
#pragma unroll
        for (int t = 0; t < 5; t++) {
            const int asw = (q ^ (((m + t) >> 1) & 3)) * 16;
            bf16x8 af[4], bfr[4];
#pragma unroll
            for (int i = 0; i < 4; i++)
                af[i] = *(const bf16x8*)((const char*)sA + (wr + i * 16 + m + t) * 64 + asw);
#pragma unroll
            for (int j = 0; j < 4; j++)
                bfr[j] = *(const bf16x8*)((const char*)sB + (t * 128 + wc + j * 16 + m) * 64 + bsw);
#pragma unroll
            for (int i = 0; i < 4; i++)
#pragma unroll
                for (int j = 0; j < 4; j++)
                    acc[i][j] = __builtin_amdgcn_mfma_f32_16x16x32_bf16(
                        af[i], bfr[j], acc[i][j], 0, 0, 0);
        }
        __syncthreads();
    }

    // ---- pos phase: 4 K-chunks, 3 taps each ----
    for (int kc = 0; kc < 128; kc += 32) {
        // stage A: rows l0..l0+129 of posp (130 rows x 64B), 3 rounds
#pragma unroll
        for (int r = 0; r < 3; r++) {
            int s = r * 256 + tid;
            int row = s >> 2; if (row > 129) row = 129;
            int c = (s & 3) ^ ((row >> 1) & 3);
            const char* src = (const char*)(posp + (size_t)(b * LPP + l0 + row) * 128 + kc) + c * 16;
            cp16(src, (char*)sA + s * 16);
        }
        // stage B: 3 taps x 128 rows x 64B, 6 rounds
#pragma unroll
        for (int r = 0; r < 6; r++) {
            int s = r * 256 + tid;
            int tap = s >> 9;
            int n = (s >> 2) & 127;
            int c = (s & 3) ^ ((n >> 1) & 3);
            const char* src = (const char*)(wcp + (size_t)(tap * KOUT + n0 + n) * 128 + kc) + c * 16;
            cp16(src, (char*)sB + s * 16);
        }
        __syncthreads();
#pragma unroll
        for (int t = 0; t < 3; t++) {
            const int asw = (q ^ (((m + t) >> 1) & 3)) * 16;
            bf16x8 af[4], bfr[4];
#pragma unroll
            for (int i = 0; i < 4; i++)
                af[i] = *(const bf16x8*)((const char*)sA + (wr + i * 16 + m + t) * 64 + asw);
#pragma unroll
            for (int j = 0; j < 4; j++)
                bfr[j] = *(const bf16x8*)((const char*)sB + (t * 128 + wc + j * 16 + m) * 64 + bsw);
#pragma unroll
            for (int i = 0; i < 4; i++)
#pragma unroll
                for (int j = 0; j < 4; j++)
                    acc[i][j] = __builtin_amdgcn_mfma_f32_16x16x32_bf16(
                        af[i], bfr[j], acc[i][j], 0, 0, 0);
        }
        __syncthreads();
    }

    const float* corrb = corr + b * 2 * KOUT;
#pragma unroll
    for (int j = 0; j < 4; j++) {
        int col = n0 + wc + j * 16 + m;
        float mx = -3.4e38f;
#pragma unroll
        for (int i = 0; i < 4; i++)
#pragma unroll
            for (int r = 0; r < 4; r++) {
                float v = acc[i][j][r];
                int l = l0 + wr + i * 16 + q * 4 + r;
                if (l == 0)      v -= corrb[col];
                if (l == L_ - 1) v -= corrb[KOUT + col];
                mx = fmaxf(mx, v);
            }
        mx = fmaxf(mx, __shfl_xor(mx, 16, 64));
        mx = fmaxf(mx, __shfl_xor(mx, 32, 64));
        if (q == 0) atomicMax(&pooled[b * KOUT + col], enc_f(mx));
    }
}

// ---------------------------------------------------------------------------
__global__ void lin1_k(const unsigned* __restrict__ pooled,
                       const float* __restrict__ conv_b,
                       const float* __restrict__ lin1_w,
                       const float* __restrict__ lin1_b,
                       float* __restrict__ com) {
    int bid = blockIdx.x;
    int wave = threadIdx.x >> 6, lane = threadIdx.x & 63;
    int b = bid >> 7;
    int h = (bid & 127) * 4 + wave;
    const float* w = lin1_w + (size_t)h * KOUT;
    const unsigned* pb = pooled + b * KOUT;
    float s = 0.f;
#pragma unroll
    for (int i = 0; i < 8; i++) {
        int k = lane + 64 * i;
        s += (dec_f(pb[k]) + conv_b[k]) * w[k];
    }
#pragma unroll
    for (int off = 32; off > 0; off >>= 1) s += __shfl_down(s, off, 64);
    if (lane == 0) com[(size_t)b * COMW + 1536 + h] = tanhf(s + lin1_b[h]);
}

__global__ void lin2_k(const float* __restrict__ com,
                       const float* __restrict__ lin2_w,
                       const float* __restrict__ lin2_b,
                       float* __restrict__ out) {
    int b = blockIdx.x;
    int wave = threadIdx.x >> 6, lane = threadIdx.x & 63;
    int t = blockIdx.y * 4 + wave;
    if (t >= T_) return;
    const float* w = lin2_w + (size_t)t * COMW;
    const float* c = com + (size_t)b * COMW;
    float s = 0.f;
#pragma unroll
    for (int i = 0; i < 32; i++) {
        int k = lane + 64 * i;
        s += c[k] * w[k];
    }
#pragma unroll
    for (int off = 32; off > 0; off >>= 1) s += __shfl_down(s, off, 64);
    if (lane == 0) out[b * T_ + t] = s + lin2_b[t];
}

// ---------------------------------------------------------------------------
extern "C" void kernel_launch(void* const* d_in, const int* in_sizes, int n_in,
                              void* d_out, int out_size, void* d_ws, size_t ws_size,
                              hipStream_t stream) {
    const int*   context = (const int*)d_in[0];
    const int*   sidx    = (const int*)d_in[1];
    const int*   oidx    = (const int*)d_in[2];
    const int*   sdis    = (const int*)d_in[3];
    const int*   odis    = (const int*)d_in[4];
    const float* etab    = (const float*)d_in[5];
    const float* ptab    = (const float*)d_in[6];
    const float* conv_w  = (const float*)d_in[7];
    const float* conv_b  = (const float*)d_in[8];
    const float* lin1_w  = (const float*)d_in[9];
    const float* lin1_b  = (const float*)d_in[10];
    const float* lin2_w  = (const float*)d_in[11];
    const float* lin2_b  = (const float*)d_in[12];
    float* out = (float*)d_out;

    char* ws = (char*)d_ws;
    size_t off = 0;
    __hip_bfloat16* embp = (__hip_bfloat16*)(ws + off);
    off += (size_t)B_ * LE * E_ * 2;             // 16.9 MB
    off = (off + 255) & ~(size_t)255;
    __hip_bfloat16* posp = (__hip_bfloat16*)(ws + off);
    off += (size_t)B_ * LPP * 128 * 2;           // 8.4 MB
    off = (off + 255) & ~(size_t)255;
    __hip_bfloat16* wce = (__hip_bfloat16*)(ws + off);
    off += (size_t)5 * KOUT * E_ * 2;            // 1.3 MB
    off = (off + 255) & ~(size_t)255;
    __hip_bfloat16* wcp = (__hip_bfloat16*)(ws + off);
    off += (size_t)3 * KOUT * 128 * 2;           // 0.4 MB
    off = (off + 255) & ~(size_t)255;
    __hip_bfloat16* wcorr = (__hip_bfloat16*)(ws + off);
    off += (size_t)2 * KOUT * E_ * 2;            // 0.5 MB
    off = (off + 255) & ~(size_t)255;
    float* corr = (float*)(ws + off);
    off += (size_t)B_ * 2 * KOUT * 4;            // 256 KB
    off = (off + 255) & ~(size_t)255;
    unsigned* pooled = (unsigned*)(ws + off);
    off += (size_t)B_ * KOUT * 4;                // 128 KB
    off = (off + 255) & ~(size_t)255;
    float* com = (float*)(ws + off);
    off += (size_t)B_ * COMW * 4;                // 512 KB

    prep<<<dim3(SEC_END), dim3(256), 0, stream>>>(
        conv_w, context, sidx, oidx, sdis, odis, etab, ptab,
        wce, wcp, wcorr, embp, posp, com, pooled);
    corr_k<<<dim3(4096), dim3(256), 0, stream>>>(context, etab, wcorr, corr);
    conv_gemm_pool<<<dim3(256, 4), dim3(256), 0, stream>>>(embp, posp, wce, wcp, corr, pooled);
    lin1_k<<<dim3(8192), dim3(256), 0, stream>>>(pooled, conv_b, lin1_w, lin1_b, com);
    lin2_k<<<dim3(B_, 14), dim3(256), 0, stream>>>(com, lin2_w, lin2_b, out);
}